// Round 1
// 355.544 us; speedup vs baseline: 1.0296x; 1.0296x over previous
//
#include <hip/hip_runtime.h>
#include <hip/hip_bf16.h>

using bf16_t = __bf16;
using bf16x8 = __attribute__((ext_vector_type(8))) __bf16;
using bf16x4 = __attribute__((ext_vector_type(4))) __bf16;
using bf16x2 = __attribute__((ext_vector_type(2))) __bf16;
using f32x4  = __attribute__((ext_vector_type(4))) float;

#define S_  2048
#define D_  1024

typedef __attribute__((address_space(1))) unsigned int glb_u32;
typedef __attribute__((address_space(3))) unsigned int lds_u32;

__device__ __forceinline__ void async_cp16(const void* g, void* lds) {
    __builtin_amdgcn_global_load_lds(
        (glb_u32*)(unsigned long long)g,
        (lds_u32*)(unsigned int)(unsigned long long)lds,
        16, 0, 0);
}

// ---------------- f32 -> bf16 casts ----------------
__global__ __launch_bounds__(256) void cast_f32_bf16(const float* __restrict__ s,
                                                     bf16_t* __restrict__ d, int n4) {
    int i = blockIdx.x * 256 + threadIdx.x;
    if (i >= n4) return;
    float4 f = reinterpret_cast<const float4*>(s)[i];
    bf16x4 o;
    o[0] = (bf16_t)f.x; o[1] = (bf16_t)f.y; o[2] = (bf16_t)f.z; o[3] = (bf16_t)f.w;
    reinterpret_cast<bf16x4*>(d)[i] = o;
}

__global__ __launch_bounds__(256) void cast2_f32_bf16(const float* __restrict__ a, const float* __restrict__ b,
                                                      bf16_t* __restrict__ oa, bf16_t* __restrict__ ob, int n4) {
    int i = blockIdx.x * 256 + threadIdx.x;
    if (i >= n4) return;
    const float* s = blockIdx.y ? b : a;
    bf16_t*      d = blockIdx.y ? ob : oa;
    float4 f = reinterpret_cast<const float4*>(s)[i];
    bf16x4 o;
    o[0] = (bf16_t)f.x; o[1] = (bf16_t)f.y; o[2] = (bf16_t)f.z; o[3] = (bf16_t)f.w;
    reinterpret_cast<bf16x4*>(d)[i] = o;
}

__global__ __launch_bounds__(256) void cast4_f32_bf16(const float* __restrict__ a, const float* __restrict__ b,
                                                      const float* __restrict__ c, const float* __restrict__ dd,
                                                      bf16_t* __restrict__ oa, bf16_t* __restrict__ ob,
                                                      bf16_t* __restrict__ oc, bf16_t* __restrict__ od, int n4) {
    int i = blockIdx.x * 256 + threadIdx.x;
    if (i >= n4) return;
    const float* s; bf16_t* d;
    int w = blockIdx.y;
    if      (w == 0) { s = a;  d = oa; }
    else if (w == 1) { s = b;  d = ob; }
    else if (w == 2) { s = c;  d = oc; }
    else             { s = dd; d = od; }
    float4 f = reinterpret_cast<const float4*>(s)[i];
    bf16x4 o;
    o[0] = (bf16_t)f.x; o[1] = (bf16_t)f.y; o[2] = (bf16_t)f.z; o[3] = (bf16_t)f.w;
    reinterpret_cast<bf16x4*>(d)[i] = o;
}

// ---------------- GEMM: C[M x 1024] = A[M x 1024] * Bt[1024 x 1024]^T ----------------
// OUTMODE 0: bf16 row-major (x scale); 1: f32 row-major; 2: bf16 transposed to
//            Vt[((m>>11)*16 + (n>>6))*64 + (n&63)][m&2047]  (per-head V^T layout)
template <int OUTMODE>
__global__ __launch_bounds__(256) void gemm_bt(const bf16_t* __restrict__ A,
                                               const bf16_t* __restrict__ Bt,
                                               void* __restrict__ Cv, float scale) {
    __shared__ bf16_t As[128 * 32];
    __shared__ bf16_t Bs[128 * 32];
    const int K = 1024;
    int tid  = threadIdx.x;
    int lane = tid & 63;
    int w    = tid >> 6;
    int l15  = lane & 15, quad = lane >> 4;
    int m0 = blockIdx.y * 128, n0 = blockIdx.x * 128;
    int wm = (w >> 1) * 64, wn = (w & 1) * 64;

    const bf16_t* Ag = A  + (size_t)(m0 + (tid >> 2)) * K + (tid & 3) * 8;
    const bf16_t* Bg = Bt + (size_t)(n0 + (tid >> 2)) * K + (tid & 3) * 8;
    bf16_t* Asw = As + tid * 8;
    bf16_t* Bsw = Bs + tid * 8;

    f32x4 acc[4][4] = {};

    for (int k0 = 0; k0 < K; k0 += 32) {
        __syncthreads();
        async_cp16(Ag + k0,                    Asw);
        async_cp16(Ag + k0 + (size_t)64 * K,   Asw + 2048);
        async_cp16(Bg + k0,                    Bsw);
        async_cp16(Bg + k0 + (size_t)64 * K,   Bsw + 2048);
        __syncthreads();
        bf16x8 af[4], bfr[4];
#pragma unroll
        for (int t = 0; t < 4; t++) {
            af[t]  = *reinterpret_cast<const bf16x8*>(&As[(wm + t * 16 + l15) * 32 + quad * 8]);
            bfr[t] = *reinterpret_cast<const bf16x8*>(&Bs[(wn + t * 16 + l15) * 32 + quad * 8]);
        }
#pragma unroll
        for (int mt = 0; mt < 4; mt++)
#pragma unroll
            for (int nt = 0; nt < 4; nt++)
                acc[mt][nt] = __builtin_amdgcn_mfma_f32_16x16x32_bf16(af[mt], bfr[nt], acc[mt][nt], 0, 0, 0);
    }

#pragma unroll
    for (int mt = 0; mt < 4; mt++)
#pragma unroll
        for (int nt = 0; nt < 4; nt++) {
            if (OUTMODE == 2) {
                int m = m0 + wm + mt * 16 + quad * 4;   // s-dim base (4 consecutive)
                int n = n0 + wn + nt * 16 + l15;        // d-dim
                bf16x4 o4;
#pragma unroll
                for (int r = 0; r < 4; r++) o4[r] = (bf16_t)(acc[mt][nt][r] * scale);
                size_t vrow = (size_t)((m >> 11) * 16 + (n >> 6)) * 64 + (n & 63);
                *reinterpret_cast<bf16x4*>(&((bf16_t*)Cv)[vrow * S_ + (m & 2047)]) = o4;
            } else {
#pragma unroll
                for (int r = 0; r < 4; r++) {
                    int m = m0 + wm + mt * 16 + quad * 4 + r;
                    int n = n0 + wn + nt * 16 + l15;
                    size_t idx = (size_t)m * 1024 + n;
                    if (OUTMODE == 1) reinterpret_cast<float*>(Cv)[idx] = acc[mt][nt][r] * scale;
                    else              reinterpret_cast<bf16_t*>(Cv)[idx] = (bf16_t)(acc[mt][nt][r] * scale);
                }
            }
        }
}

// ---------------- fused masked attention ----------------
// QBLK=64 (4 waves x 16 q-rows) -> 2048 WGs: backfill queue + 2x tail waves for
// the heaviest batch. LPT tile order (batches sorted by nkb desc, read from
// device vlen) so heavy tiles dispatch first; heads clustered per-XCD for K/V
// L2 locality. K/V double-buffered via swizzled-source global_load_lds; the
// 16B-slot XOR (slot ^ (row&7)) is applied on the GLOBAL source address at
// staging and on every LDS read address, so LDS stays lane-linear for the DMA.
// Q staged through the K1 buffer (prologue), epilogue transpose reuses K0.
__global__ __launch_bounds__(256) void attn_fused(const bf16_t* __restrict__ Qp,
                                                  const bf16_t* __restrict__ Kp,
                                                  const bf16_t* __restrict__ Vt,
                                                  const int* __restrict__ vlen_p,
                                                  bf16_t* __restrict__ Out) {
    __shared__ bf16_t smem[4][64 * 64];   // [0]=K0 (+epilogue T), [1]=V0, [2]=K1 (+Q prologue), [3]=V1

    int tid  = threadIdx.x;
    int lane = tid & 63, w = tid >> 6;
    int l15  = lane & 15, quad = lane >> 4;

    // ---- LPT + XCD-clustered tile decode ----
    int nk[4], ord[4] = {0, 1, 2, 3};
#pragma unroll
    for (int i = 0; i < 4; i++) nk[i] = (vlen_p[i] + 63) >> 6;
#pragma unroll
    for (int i = 0; i < 3; i++)
#pragma unroll
        for (int j = 0; j < 3 - i; j++)
            if (nk[ord[j + 1]] > nk[ord[j]]) { int t = ord[j]; ord[j] = ord[j + 1]; ord[j + 1] = t; }

    int bid  = blockIdx.x;
    int b    = ord[bid >> 9];              // heaviest batch first in dispatch order
    int t    = bid & 511;
    int h    = (t & 7) * 2 + ((t >> 3) & 1);  // 2 heads per XCD slot -> K/V L2 locality
    int qblk = t >> 4;                        // 0..31
    int vlen = vlen_p[b];
    int nkb  = (vlen + 63) >> 6;

    const bf16_t* Qg = Qp + (size_t)(b * S_ + qblk * 64) * D_ + h * 64;
    const bf16_t* Kg = Kp + (size_t)b * S_ * D_ + h * 64;
    const bf16_t* Vg = Vt + (size_t)(b * 16 + h) * 64 * S_;

    // swizzled-source staging: LDS physical [row][s] holds logical slot s^(row&7)
    auto stage = [&](const bf16_t* g, size_t rstride, bf16_t* lds) {
#pragma unroll
        for (int j = 0; j < 2; j++) {
            int linear = j * 256 + tid;
            int row = linear >> 3, s = linear & 7;
            async_cp16(g + (size_t)row * rstride + (s ^ (row & 7)) * 8, lds + linear * 8);
        }
    };

    // prologue: Q -> smem[2], K0 -> smem[0], V0 -> smem[1]
    stage(Qg, D_, smem[2]);
    stage(Kg, D_, smem[0]);
    stage(Vg, S_, smem[1]);
    __syncthreads();

    bf16x8 qf[2];
    {
        int row = w * 16 + l15, x = row & 7;
#pragma unroll
        for (int kk = 0; kk < 2; kk++)
            qf[kk] = *reinterpret_cast<const bf16x8*>(&smem[2][row * 64 + ((kk * 4 + quad) ^ x) * 8]);
    }
    __syncthreads();   // all waves done with Q before kb=0 prefetch overwrites smem[2]

    f32x4 o[4] = {};
    float l_st = 0.f;

    for (int kb = 0; kb < nkb; kb++) {
        int cur = kb & 1;
        if (kb + 1 < nkb) {
            int nxt = cur ^ 1;
            stage(Kg + (size_t)(kb + 1) * 64 * D_, D_, smem[nxt * 2]);
            stage(Vg + (kb + 1) * 64,              S_, smem[nxt * 2 + 1]);
        }
        const bf16_t* Kc = smem[cur * 2];
        const bf16_t* Vc = smem[cur * 2 + 1];

        // St = K Q^T  (rows = k, cols = this wave's 16 q)
        f32x4 sc[4] = {};
#pragma unroll
        for (int nt = 0; nt < 4; nt++) {
            int row = nt * 16 + l15, x = row & 7;
#pragma unroll
            for (int kk = 0; kk < 2; kk++) {
                bf16x8 kf = *reinterpret_cast<const bf16x8*>(&Kc[row * 64 + ((kk * 4 + quad) ^ x) * 8]);
                sc[nt] = __builtin_amdgcn_mfma_f32_16x16x32_bf16(kf, qf[kk], sc[nt], 0, 0, 0);
            }
        }

        // max-free softmax: p = exp2(st), scale baked into Q projection
        bool partial = (vlen & 63) && (kb == nkb - 1);
        bf16x8 pf[2];
        float lacc = 0.f;
        if (!partial) {
#pragma unroll
            for (int nt = 0; nt < 4; nt++)
#pragma unroll
                for (int r = 0; r < 4; r++) {
                    float p = __builtin_exp2f(sc[nt][r]);
                    lacc += p;
                    pf[nt >> 1][(nt & 1) * 4 + r] = (bf16_t)p;
                }
        } else {
#pragma unroll
            for (int nt = 0; nt < 4; nt++)
#pragma unroll
                for (int r = 0; r < 4; r++) {
                    float p = __builtin_exp2f(sc[nt][r]);
                    if (kb * 64 + nt * 16 + quad * 4 + r >= vlen) p = 0.f;
                    lacc += p;
                    pf[nt >> 1][(nt & 1) * 4 + r] = (bf16_t)p;
                }
        }
        l_st += lacc;

        // O^T += V^T P^T
#pragma unroll
        for (int np = 0; np < 2; np++)
#pragma unroll
            for (int dt = 0; dt < 4; dt++) {
                int row = dt * 16 + l15, x = row & 7;
                int off = (quad & 1) * 4;
                bf16x4 v0 = *reinterpret_cast<const bf16x4*>(&Vc[row * 64 + (((np * 4)     + (quad >> 1)) ^ x) * 8 + off]);
                bf16x4 v1 = *reinterpret_cast<const bf16x4*>(&Vc[row * 64 + (((np * 4 + 2) + (quad >> 1)) ^ x) * 8 + off]);
                bf16x8 vf;
#pragma unroll
                for (int j = 0; j < 4; j++) { vf[j] = v0[j]; vf[4 + j] = v1[j]; }
                o[dt] = __builtin_amdgcn_mfma_f32_16x16x32_bf16(vf, pf[np], o[dt], 0, 0, 0);
            }

        __syncthreads();  // drains prefetch vmcnt + guards cur-buffer reuse
    }

    float l = l_st;
    l += __shfl_xor(l, 16);
    l += __shfl_xor(l, 32);
    float inv = 1.0f / l;

    // epilogue: O^T -> swizzled T (reuse K0) -> coalesced row-major store
    bf16_t* T = smem[0];
    {
        int row = w * 16 + l15, x = row & 7;
#pragma unroll
        for (int dt = 0; dt < 4; dt++) {
            bf16x4 o4;
#pragma unroll
            for (int r = 0; r < 4; r++) o4[r] = (bf16_t)(o[dt][r] * inv);
            int slot = dt * 2 + (quad >> 1);
            *reinterpret_cast<bf16x4*>(&T[row * 64 + (slot ^ x) * 8 + (quad & 1) * 4]) = o4;
        }
    }
    __syncthreads();
    {
        int row = tid >> 2, ch = tid & 3, x = row & 7;
        size_t obase = (size_t)(b * S_ + qblk * 64 + row) * D_ + h * 64 + ch * 16;
        bf16x8 f0 = *reinterpret_cast<const bf16x8*>(&T[row * 64 + ((ch * 2)     ^ x) * 8]);
        bf16x8 f1 = *reinterpret_cast<const bf16x8*>(&T[row * 64 + ((ch * 2 + 1) ^ x) * 8]);
        *reinterpret_cast<bf16x8*>(&Out[obase])     = f0;
        *reinterpret_cast<bf16x8*>(&Out[obase + 8]) = f1;
    }
}

extern "C" void kernel_launch(void* const* d_in, const int* in_sizes, int n_in,
                              void* d_out, int out_size, void* d_ws, size_t ws_size,
                              hipStream_t stream) {
    const float* q  = (const float*)d_in[0];
    const float* k  = (const float*)d_in[1];
    const float* v  = (const float*)d_in[2];
    const int*   vl = (const int*)d_in[3];
    const float* Wq = (const float*)d_in[4];
    const float* Wk = (const float*)d_in[5];
    const float* Wv = (const float*)d_in[6];
    const float* Wo = (const float*)d_in[7];
    float* out = (float*)d_out;

    bf16_t* ws = (bf16_t*)d_ws;
    const size_t SD = (size_t)8192 * 1024;
    const size_t WW = (size_t)1024 * 1024;
    bf16_t* tmpA = ws;             // q bf16, then v bf16
    bf16_t* tmpB = ws + SD;        // k bf16, then attn output
    bf16_t* Qp   = ws + 2 * SD;
    bf16_t* Kp   = ws + 3 * SD;
    bf16_t* Vt   = ws + 4 * SD;    // per-head V^T: [(b*16+h)*64+d][s]
    bf16_t* Wqb  = ws + 5 * SD;
    bf16_t* Wkb  = Wqb + WW;
    bf16_t* Wvb  = Wqb + 2 * WW;
    bf16_t* Wob  = Wqb + 3 * WW;
    // total: 5*SD + 4*WW elems = 92.3 MB (same footprint as before, known-good)

    const float cs = 0.18033688f;  // (1/8)*log2(e) baked into Q projection
    dim3 blk(256);
    dim3 gg(8, 64);

    cast4_f32_bf16<<<dim3(1024, 4), blk, 0, stream>>>(Wq, Wk, Wv, Wo, Wqb, Wkb, Wvb, Wob, 262144);
    cast2_f32_bf16<<<dim3(8192, 2), blk, 0, stream>>>(q, k, tmpA, tmpB, 2097152);

    gemm_bt<0><<<gg, blk, 0, stream>>>(tmpA, Wqb, Qp, cs);
    gemm_bt<0><<<gg, blk, 0, stream>>>(tmpB, Wkb, Kp, 1.0f);
    cast_f32_bf16<<<dim3(8192), blk, 0, stream>>>(v, tmpA, 2097152);
    gemm_bt<2><<<gg, blk, 0, stream>>>(tmpA, Wvb, Vt, 1.0f);

    attn_fused<<<dim3(2048), blk, 0, stream>>>(Qp, Kp, Vt, vl, tmpB);
    gemm_bt<1><<<gg, blk, 0, stream>>>(tmpB, Wob, out, 1.0f);
}

// Round 2
// 322.947 us; speedup vs baseline: 1.1335x; 1.1009x over previous
//
#include <hip/hip_runtime.h>
#include <hip/hip_bf16.h>

using bf16_t = __bf16;
using bf16x8 = __attribute__((ext_vector_type(8))) __bf16;
using bf16x4 = __attribute__((ext_vector_type(4))) __bf16;
using bf16x2 = __attribute__((ext_vector_type(2))) __bf16;
using f32x4  = __attribute__((ext_vector_type(4))) float;

#define S_  2048
#define D_  1024

typedef __attribute__((address_space(1))) unsigned int glb_u32;
typedef __attribute__((address_space(3))) unsigned int lds_u32;

__device__ __forceinline__ void async_cp16(const void* g, void* lds) {
    __builtin_amdgcn_global_load_lds(
        (glb_u32*)(unsigned long long)g,
        (lds_u32*)(unsigned int)(unsigned long long)lds,
        16, 0, 0);
}

// ---------------- f32 -> bf16 casts ----------------
__global__ __launch_bounds__(256) void cast_f32_bf16(const float* __restrict__ s,
                                                     bf16_t* __restrict__ d, int n4) {
    int i = blockIdx.x * 256 + threadIdx.x;
    if (i >= n4) return;
    float4 f = reinterpret_cast<const float4*>(s)[i];
    bf16x4 o;
    o[0] = (bf16_t)f.x; o[1] = (bf16_t)f.y; o[2] = (bf16_t)f.z; o[3] = (bf16_t)f.w;
    reinterpret_cast<bf16x4*>(d)[i] = o;
}

__global__ __launch_bounds__(256) void cast2_f32_bf16(const float* __restrict__ a, const float* __restrict__ b,
                                                      bf16_t* __restrict__ oa, bf16_t* __restrict__ ob, int n4) {
    int i = blockIdx.x * 256 + threadIdx.x;
    if (i >= n4) return;
    const float* s = blockIdx.y ? b : a;
    bf16_t*      d = blockIdx.y ? ob : oa;
    float4 f = reinterpret_cast<const float4*>(s)[i];
    bf16x4 o;
    o[0] = (bf16_t)f.x; o[1] = (bf16_t)f.y; o[2] = (bf16_t)f.z; o[3] = (bf16_t)f.w;
    reinterpret_cast<bf16x4*>(d)[i] = o;
}

__global__ __launch_bounds__(256) void cast4_f32_bf16(const float* __restrict__ a, const float* __restrict__ b,
                                                      const float* __restrict__ c, const float* __restrict__ dd,
                                                      bf16_t* __restrict__ oa, bf16_t* __restrict__ ob,
                                                      bf16_t* __restrict__ oc, bf16_t* __restrict__ od, int n4) {
    int i = blockIdx.x * 256 + threadIdx.x;
    if (i >= n4) return;
    const float* s; bf16_t* d;
    int w = blockIdx.y;
    if      (w == 0) { s = a;  d = oa; }
    else if (w == 1) { s = b;  d = ob; }
    else if (w == 2) { s = c;  d = oc; }
    else             { s = dd; d = od; }
    float4 f = reinterpret_cast<const float4*>(s)[i];
    bf16x4 o;
    o[0] = (bf16_t)f.x; o[1] = (bf16_t)f.y; o[2] = (bf16_t)f.z; o[3] = (bf16_t)f.w;
    reinterpret_cast<bf16x4*>(d)[i] = o;
}

// ---------------- GEMM: C[M x 1024] = A[M x 1024] * Bt[1024 x 1024]^T ----------------
// Double-buffered LDS: next K-tile's global_load_lds issued BEFORE compute so the
// end-of-iter barrier drain is covered by 16 MFMAs (was: issue->drain->compute,
// one exposed L2 latency per K-step at only 2 WG/CU).
// XCD swizzle: bid%8 = XCD; each XCD owns 8 m-blocks x all n-blocks -> its A band
// (2MB) + full B (2MB) are L2-resident instead of A being refetched per-XCD.
// OUTMODE 0: bf16 row-major (x scale); 1: f32 row-major; 2: bf16 transposed to
//            per-head V^T layout, with each 32-wide s-block PERMUTED into MFMA
//            A-fragment order: pos = q*8 + hi*4 + r  for s = q*4 + hi*16 + r.
//            (lets attn read V-frags as one contiguous b128, no repacking)
template <int OUTMODE>
__global__ __launch_bounds__(256) void gemm_bt(const bf16_t* __restrict__ A,
                                               const bf16_t* __restrict__ Bt,
                                               void* __restrict__ Cv, float scale) {
    __shared__ bf16_t As[2][128 * 32];
    __shared__ bf16_t Bs[2][128 * 32];
    const int K = 1024;
    int tid  = threadIdx.x;
    int lane = tid & 63;
    int w    = tid >> 6;
    int l15  = lane & 15, quad = lane >> 4;

    int bid = blockIdx.y * gridDim.x + blockIdx.x;
    int xcd = bid & 7, idx = bid >> 3;
    int m0 = (xcd * 8 + (idx & 7)) * 128;   // 8 m-blocks per XCD
    int n0 = (idx >> 3) * 128;
    int wm = (w >> 1) * 64, wn = (w & 1) * 64;

    const bf16_t* Ag = A  + (size_t)(m0 + (tid >> 2)) * K + (tid & 3) * 8;
    const bf16_t* Bg = Bt + (size_t)(n0 + (tid >> 2)) * K + (tid & 3) * 8;

    f32x4 acc[4][4] = {};

    async_cp16(Ag,                  &As[0][tid * 8]);
    async_cp16(Ag + (size_t)64 * K, &As[0][tid * 8 + 2048]);
    async_cp16(Bg,                  &Bs[0][tid * 8]);
    async_cp16(Bg + (size_t)64 * K, &Bs[0][tid * 8 + 2048]);
    __syncthreads();

    for (int k0 = 0; k0 < K; k0 += 32) {
        int cur = (k0 >> 5) & 1;
        if (k0 + 32 < K) {
            int nxt = cur ^ 1;
            async_cp16(Ag + k0 + 32,                  &As[nxt][tid * 8]);
            async_cp16(Ag + k0 + 32 + (size_t)64 * K, &As[nxt][tid * 8 + 2048]);
            async_cp16(Bg + k0 + 32,                  &Bs[nxt][tid * 8]);
            async_cp16(Bg + k0 + 32 + (size_t)64 * K, &Bs[nxt][tid * 8 + 2048]);
        }
        bf16x8 af[4], bfr[4];
#pragma unroll
        for (int t = 0; t < 4; t++) {
            af[t]  = *reinterpret_cast<const bf16x8*>(&As[cur][(wm + t * 16 + l15) * 32 + quad * 8]);
            bfr[t] = *reinterpret_cast<const bf16x8*>(&Bs[cur][(wn + t * 16 + l15) * 32 + quad * 8]);
        }
#pragma unroll
        for (int mt = 0; mt < 4; mt++)
#pragma unroll
            for (int nt = 0; nt < 4; nt++)
                acc[mt][nt] = __builtin_amdgcn_mfma_f32_16x16x32_bf16(af[mt], bfr[nt], acc[mt][nt], 0, 0, 0);
        __syncthreads();   // drains prefetch vmcnt + guards buffer reuse
    }

#pragma unroll
    for (int mt = 0; mt < 4; mt++)
#pragma unroll
        for (int nt = 0; nt < 4; nt++) {
            if (OUTMODE == 2) {
                int m = m0 + wm + mt * 16 + quad * 4;   // s-dim base (4 consecutive)
                int n = n0 + wn + nt * 16 + l15;        // d-dim
                bf16x4 o4;
#pragma unroll
                for (int r = 0; r < 4; r++) o4[r] = (bf16_t)(acc[mt][nt][r] * scale);
                size_t vrow = (size_t)((m >> 11) * 16 + (n >> 6)) * 64 + (n & 63);
                int ml = m & 2047;
                // permute s within its 32-block into A-frag order (4-aligned move)
                int mp = (ml & ~31) | (((ml >> 2) & 3) << 3) | (((ml >> 4) & 1) << 2);
                *reinterpret_cast<bf16x4*>(&((bf16_t*)Cv)[vrow * S_ + mp]) = o4;
            } else {
#pragma unroll
                for (int r = 0; r < 4; r++) {
                    int m = m0 + wm + mt * 16 + quad * 4 + r;
                    int n = n0 + wn + nt * 16 + l15;
                    size_t idx2 = (size_t)m * 1024 + n;
                    if (OUTMODE == 1) reinterpret_cast<float*>(Cv)[idx2] = acc[mt][nt][r] * scale;
                    else              reinterpret_cast<bf16_t*>(Cv)[idx2] = (bf16_t)(acc[mt][nt][r] * scale);
                }
            }
        }
}

// ---------------- fused masked attention ----------------
// QBLK=64 (4 waves x 16 q-rows), 2048 WGs, LPT batch order + head clustering.
// K/V double-buffered via swizzled-source global_load_lds (16B-slot XOR row&7,
// applied on the GLOBAL source address and on every LDS read).
// V^T arrives pre-permuted into A-frag k-order (see gemm OUTMODE 2), so PV
// fragments are single contiguous b128 reads -- no b64 pairs, no repacking.
__global__ __launch_bounds__(256) void attn_fused(const bf16_t* __restrict__ Qp,
                                                  const bf16_t* __restrict__ Kp,
                                                  const bf16_t* __restrict__ Vt,
                                                  const int* __restrict__ vlen_p,
                                                  bf16_t* __restrict__ Out) {
    __shared__ bf16_t smem[4][64 * 64];   // [0]=K0 (+epilogue T), [1]=V0, [2]=K1 (+Q prologue), [3]=V1

    int tid  = threadIdx.x;
    int lane = tid & 63, w = tid >> 6;
    int l15  = lane & 15, quad = lane >> 4;

    // ---- LPT + XCD-clustered tile decode ----
    int nk[4], ord[4] = {0, 1, 2, 3};
#pragma unroll
    for (int i = 0; i < 4; i++) nk[i] = (vlen_p[i] + 63) >> 6;
#pragma unroll
    for (int i = 0; i < 3; i++)
#pragma unroll
        for (int j = 0; j < 3 - i; j++)
            if (nk[ord[j + 1]] > nk[ord[j]]) { int t = ord[j]; ord[j] = ord[j + 1]; ord[j + 1] = t; }

    int bid  = blockIdx.x;
    int b    = ord[bid >> 9];              // heaviest batch first in dispatch order
    int t    = bid & 511;
    int h    = (t & 7) * 2 + ((t >> 3) & 1);  // 2 heads per XCD slot -> K/V L2 locality
    int qblk = t >> 4;                        // 0..31
    int vlen = vlen_p[b];
    int nkb  = (vlen + 63) >> 6;

    const bf16_t* Qg = Qp + (size_t)(b * S_ + qblk * 64) * D_ + h * 64;
    const bf16_t* Kg = Kp + (size_t)b * S_ * D_ + h * 64;
    const bf16_t* Vg = Vt + (size_t)(b * 16 + h) * 64 * S_;

    // per-lane staging addresses (incremental; XOR source swizzle baked in)
    int r0 = tid >> 3, s0 = tid & 7;
    int sx = (s0 ^ (r0 & 7)) * 8;            // (r0+32)&7 == r0&7
    const bf16_t* kS0 = Kg + (size_t)r0 * D_ + sx;
    const bf16_t* kS1 = kS0 + (size_t)32 * D_;
    const bf16_t* vS0 = Vg + (size_t)r0 * S_ + sx;
    const bf16_t* vS1 = vS0 + (size_t)32 * S_;

    // prologue: Q -> smem[2], K0 -> smem[0], V0 -> smem[1]
    {
        const bf16_t* qS0 = Qg + (size_t)r0 * D_ + sx;
        async_cp16(qS0,                   smem[2] + tid * 8);
        async_cp16(qS0 + (size_t)32 * D_, smem[2] + tid * 8 + 2048);
        async_cp16(kS0, smem[0] + tid * 8);
        async_cp16(kS1, smem[0] + tid * 8 + 2048);
        async_cp16(vS0, smem[1] + tid * 8);
        async_cp16(vS1, smem[1] + tid * 8 + 2048);
    }
    __syncthreads();

    bf16x8 qf[2];
    {
        int row = w * 16 + l15, x = row & 7;
#pragma unroll
        for (int kk = 0; kk < 2; kk++)
            qf[kk] = *reinterpret_cast<const bf16x8*>(&smem[2][row * 64 + ((kk * 4 + quad) ^ x) * 8]);
    }
    __syncthreads();   // all waves done with Q before kb=0 prefetch overwrites smem[2]

    f32x4 o[4] = {};
    float l_st = 0.f;

    for (int kb = 0; kb < nkb; kb++) {
        int cur = kb & 1;
        if (kb + 1 < nkb) {
            int nxt = cur ^ 1;
            kS0 += (size_t)64 * D_; kS1 += (size_t)64 * D_;
            vS0 += 64;              vS1 += 64;
            async_cp16(kS0, smem[nxt * 2]     + tid * 8);
            async_cp16(kS1, smem[nxt * 2]     + tid * 8 + 2048);
            async_cp16(vS0, smem[nxt * 2 + 1] + tid * 8);
            async_cp16(vS1, smem[nxt * 2 + 1] + tid * 8 + 2048);
        }
        const bf16_t* Kc = smem[cur * 2];
        const bf16_t* Vc = smem[cur * 2 + 1];

        // St = K Q^T  (rows = k, cols = this wave's 16 q)
        f32x4 sc[4] = {};
#pragma unroll
        for (int nt = 0; nt < 4; nt++) {
            int row = nt * 16 + l15, x = row & 7;
#pragma unroll
            for (int kk = 0; kk < 2; kk++) {
                bf16x8 kf = *reinterpret_cast<const bf16x8*>(&Kc[row * 64 + ((kk * 4 + quad) ^ x) * 8]);
                sc[nt] = __builtin_amdgcn_mfma_f32_16x16x32_bf16(kf, qf[kk], sc[nt], 0, 0, 0);
            }
        }

        // max-free softmax: p = exp2(st), scale baked into Q projection
        bool partial = (vlen & 63) && (kb == nkb - 1);
        bf16x8 pf[2];
        float lacc = 0.f;
        if (!partial) {
#pragma unroll
            for (int nt = 0; nt < 4; nt++)
#pragma unroll
                for (int r = 0; r < 4; r++) {
                    float p = __builtin_exp2f(sc[nt][r]);
                    lacc += p;
                    pf[nt >> 1][(nt & 1) * 4 + r] = (bf16_t)p;
                }
        } else {
#pragma unroll
            for (int nt = 0; nt < 4; nt++)
#pragma unroll
                for (int r = 0; r < 4; r++) {
                    float p = __builtin_exp2f(sc[nt][r]);
                    if (kb * 64 + nt * 16 + quad * 4 + r >= vlen) p = 0.f;
                    lacc += p;
                    pf[nt >> 1][(nt & 1) * 4 + r] = (bf16_t)p;
                }
        }
        l_st += lacc;

        // O^T += V^T P^T ; V pre-permuted -> single b128 A-frag per (np,dt)
#pragma unroll
        for (int np = 0; np < 2; np++)
#pragma unroll
            for (int dt = 0; dt < 4; dt++) {
                int row = dt * 16 + l15, x = row & 7;
                bf16x8 vf = *reinterpret_cast<const bf16x8*>(&Vc[row * 64 + ((np * 4 + quad) ^ x) * 8]);
                o[dt] = __builtin_amdgcn_mfma_f32_16x16x32_bf16(vf, pf[np], o[dt], 0, 0, 0);
            }

        __syncthreads();  // drains prefetch vmcnt + guards cur-buffer reuse
    }

    float l = l_st;
    l += __shfl_xor(l, 16);
    l += __shfl_xor(l, 32);
    float inv = 1.0f / l;

    // epilogue: O^T -> swizzled T (reuse K0) -> coalesced row-major store
    bf16_t* T = smem[0];
    {
        int row = w * 16 + l15, x = row & 7;
#pragma unroll
        for (int dt = 0; dt < 4; dt++) {
            bf16x4 o4;
#pragma unroll
            for (int r = 0; r < 4; r++) o4[r] = (bf16_t)(o[dt][r] * inv);
            int slot = dt * 2 + (quad >> 1);
            *reinterpret_cast<bf16x4*>(&T[row * 64 + (slot ^ x) * 8 + (quad & 1) * 4]) = o4;
        }
    }
    __syncthreads();
    {
        int row = tid >> 2, ch = tid & 3, x = row & 7;
        size_t obase = (size_t)(b * S_ + qblk * 64 + row) * D_ + h * 64 + ch * 16;
        bf16x8 f0 = *reinterpret_cast<const bf16x8*>(&T[row * 64 + ((ch * 2)     ^ x) * 8]);
        bf16x8 f1 = *reinterpret_cast<const bf16x8*>(&T[row * 64 + ((ch * 2 + 1) ^ x) * 8]);
        *reinterpret_cast<bf16x8*>(&Out[obase])     = f0;
        *reinterpret_cast<bf16x8*>(&Out[obase + 8]) = f1;
    }
}

extern "C" void kernel_launch(void* const* d_in, const int* in_sizes, int n_in,
                              void* d_out, int out_size, void* d_ws, size_t ws_size,
                              hipStream_t stream) {
    const float* q  = (const float*)d_in[0];
    const float* k  = (const float*)d_in[1];
    const float* v  = (const float*)d_in[2];
    const int*   vl = (const int*)d_in[3];
    const float* Wq = (const float*)d_in[4];
    const float* Wk = (const float*)d_in[5];
    const float* Wv = (const float*)d_in[6];
    const float* Wo = (const float*)d_in[7];
    float* out = (float*)d_out;

    bf16_t* ws = (bf16_t*)d_ws;
    const size_t SD = (size_t)8192 * 1024;
    const size_t WW = (size_t)1024 * 1024;
    bf16_t* tmpA = ws;             // q bf16, then v bf16
    bf16_t* tmpB = ws + SD;        // k bf16, then attn output
    bf16_t* Qp   = ws + 2 * SD;
    bf16_t* Kp   = ws + 3 * SD;
    bf16_t* Vt   = ws + 4 * SD;    // per-head V^T, s pre-permuted to A-frag order
    bf16_t* Wqb  = ws + 5 * SD;
    bf16_t* Wkb  = Wqb + WW;
    bf16_t* Wvb  = Wqb + 2 * WW;
    bf16_t* Wob  = Wqb + 3 * WW;

    const float cs = 0.18033688f;  // (1/8)*log2(e) baked into Q projection
    dim3 blk(256);
    dim3 gg(8, 64);

    cast4_f32_bf16<<<dim3(1024, 4), blk, 0, stream>>>(Wq, Wk, Wv, Wo, Wqb, Wkb, Wvb, Wob, 262144);
    cast2_f32_bf16<<<dim3(8192, 2), blk, 0, stream>>>(q, k, tmpA, tmpB, 2097152);

    gemm_bt<0><<<gg, blk, 0, stream>>>(tmpA, Wqb, Qp, cs);
    gemm_bt<0><<<gg, blk, 0, stream>>>(tmpB, Wkb, Kp, 1.0f);
    cast_f32_bf16<<<dim3(8192), blk, 0, stream>>>(v, tmpA, 2097152);
    gemm_bt<2><<<gg, blk, 0, stream>>>(tmpA, Wvb, Vt, 1.0f);

    attn_fused<<<dim3(2048), blk, 0, stream>>>(Qp, Kp, Vt, vl, tmpB);
    gemm_bt<1><<<gg, blk, 0, stream>>>(tmpB, Wob, out, 1.0f);
}

// Round 3
// 322.078 us; speedup vs baseline: 1.1365x; 1.0027x over previous
//
#include <hip/hip_runtime.h>
#include <hip/hip_bf16.h>

using bf16_t = __bf16;
using bf16x8 = __attribute__((ext_vector_type(8))) __bf16;
using bf16x4 = __attribute__((ext_vector_type(4))) __bf16;
using bf16x2 = __attribute__((ext_vector_type(2))) __bf16;
using f32x4  = __attribute__((ext_vector_type(4))) float;

#define S_  2048
#define D_  1024

typedef __attribute__((address_space(1))) unsigned int glb_u32;
typedef __attribute__((address_space(3))) unsigned int lds_u32;

__device__ __forceinline__ void async_cp16(const void* g, void* lds) {
    __builtin_amdgcn_global_load_lds(
        (glb_u32*)(unsigned long long)g,
        (lds_u32*)(unsigned int)(unsigned long long)lds,
        16, 0, 0);
}

// ---------------- weights f32 -> bf16 ----------------
__global__ __launch_bounds__(256) void cast4_f32_bf16(const float* __restrict__ a, const float* __restrict__ b,
                                                      const float* __restrict__ c, const float* __restrict__ dd,
                                                      bf16_t* __restrict__ oa, bf16_t* __restrict__ ob,
                                                      bf16_t* __restrict__ oc, bf16_t* __restrict__ od, int n4) {
    int i = blockIdx.x * 256 + threadIdx.x;
    if (i >= n4) return;
    const float* s; bf16_t* d;
    int w = blockIdx.y;
    if      (w == 0) { s = a;  d = oa; }
    else if (w == 1) { s = b;  d = ob; }
    else if (w == 2) { s = c;  d = oc; }
    else             { s = dd; d = od; }
    float4 f = reinterpret_cast<const float4*>(s)[i];
    bf16x4 o;
    o[0] = (bf16_t)f.x; o[1] = (bf16_t)f.y; o[2] = (bf16_t)f.z; o[3] = (bf16_t)f.w;
    reinterpret_cast<bf16x4*>(d)[i] = o;
}

// ---------------- fused QKV projection: 3 GEMMs, one dispatch ----------------
// C[8192 x 1024] = cast_bf16(Af32[8192 x 1024]) * W[1024 x 1024]^T  for z=0,1,2.
// A read directly as f32, converted during reg-staging (float4 loads issued
// BEFORE the MFMA block -> latency covered; ds_write after compute; one barrier
// per K-step). B (bf16 weights) via global_load_lds double-buffer.
// 1536 WGs @ 32KB LDS -> 5 WG/CU co-resident + backfill queue (the old 512-WG
// grids were 2 WG/CU lockstep with zero backfill -> exposed barrier drains).
// z=2 (V) stores per-head V^T with each 32-wide s-block permuted into MFMA
// A-frag order: pos = q*8 + hi*4 + r for s = q*4 + hi*16 + r.
__global__ __launch_bounds__(256) void qkv_gemm(const float* __restrict__ qf,
                                                const float* __restrict__ kf,
                                                const float* __restrict__ vf,
                                                const bf16_t* __restrict__ Wqb,
                                                const bf16_t* __restrict__ Wkb,
                                                const bf16_t* __restrict__ Wvb,
                                                bf16_t* __restrict__ Qp,
                                                bf16_t* __restrict__ Kp,
                                                bf16_t* __restrict__ Vt,
                                                float cs) {
    __shared__ bf16_t As[2][128 * 32];
    __shared__ bf16_t Bs[2][128 * 32];
    const int K = 1024;
    int tid  = threadIdx.x;
    int lane = tid & 63;
    int w    = tid >> 6;
    int l15  = lane & 15, quad = lane >> 4;

    int bid = blockIdx.x;
    int xcd = bid & 7, idx = bid >> 3;     // 0..191
    int z   = idx >> 6;                    // 0..2 (z-major: each XCD finishes a band before moving on)
    int rem = idx & 63;
    int m0 = (xcd * 8 + (rem & 7)) * 128;
    int n0 = (rem >> 3) * 128;
    int wm = (w >> 1) * 64, wn = (w & 1) * 64;

    const float*  Af; const bf16_t* Bt;
    if      (z == 0) { Af = qf; Bt = Wqb; }
    else if (z == 1) { Af = kf; Bt = Wkb; }
    else             { Af = vf; Bt = Wvb; }
    float scale = (z == 0) ? cs : 1.0f;

    const float*  Ag = Af + (size_t)(m0 + (tid >> 2)) * K + (tid & 3) * 8;
    const bf16_t* Bg = Bt + (size_t)(n0 + (tid >> 2)) * K + (tid & 3) * 8;

    float4 a0, a1, a2, a3;
    auto loadA = [&](int k0) {
        const float* p = Ag + k0;
        a0 = *reinterpret_cast<const float4*>(p);
        a1 = *reinterpret_cast<const float4*>(p + 4);
        a2 = *reinterpret_cast<const float4*>(p + (size_t)64 * K);
        a3 = *reinterpret_cast<const float4*>(p + (size_t)64 * K + 4);
    };
    auto storeA = [&](bf16_t* dst) {
        bf16x8 o0, o1;
        o0[0] = (bf16_t)a0.x; o0[1] = (bf16_t)a0.y; o0[2] = (bf16_t)a0.z; o0[3] = (bf16_t)a0.w;
        o0[4] = (bf16_t)a1.x; o0[5] = (bf16_t)a1.y; o0[6] = (bf16_t)a1.z; o0[7] = (bf16_t)a1.w;
        o1[0] = (bf16_t)a2.x; o1[1] = (bf16_t)a2.y; o1[2] = (bf16_t)a2.z; o1[3] = (bf16_t)a2.w;
        o1[4] = (bf16_t)a3.x; o1[5] = (bf16_t)a3.y; o1[6] = (bf16_t)a3.z; o1[7] = (bf16_t)a3.w;
        *reinterpret_cast<bf16x8*>(dst + tid * 8)        = o0;
        *reinterpret_cast<bf16x8*>(dst + tid * 8 + 2048) = o1;
    };

    f32x4 acc[4][4] = {};

    // prologue: tile 0
    loadA(0);
    async_cp16(Bg,                  &Bs[0][tid * 8]);
    async_cp16(Bg + (size_t)64 * K, &Bs[0][tid * 8 + 2048]);
    storeA(As[0]);
    __syncthreads();

    for (int k0 = 0; k0 < K; k0 += 32) {
        int cur = (k0 >> 5) & 1;
        bool more = (k0 + 32 < K);
        if (more) {
            int nxt = cur ^ 1;
            loadA(k0 + 32);
            async_cp16(Bg + k0 + 32,                  &Bs[nxt][tid * 8]);
            async_cp16(Bg + k0 + 32 + (size_t)64 * K, &Bs[nxt][tid * 8 + 2048]);
        }
        bf16x8 af[4], bfr[4];
#pragma unroll
        for (int t = 0; t < 4; t++) {
            af[t]  = *reinterpret_cast<const bf16x8*>(&As[cur][(wm + t * 16 + l15) * 32 + quad * 8]);
            bfr[t] = *reinterpret_cast<const bf16x8*>(&Bs[cur][(wn + t * 16 + l15) * 32 + quad * 8]);
        }
#pragma unroll
        for (int mt = 0; mt < 4; mt++)
#pragma unroll
            for (int nt = 0; nt < 4; nt++)
                acc[mt][nt] = __builtin_amdgcn_mfma_f32_16x16x32_bf16(af[mt], bfr[nt], acc[mt][nt], 0, 0, 0);
        if (more) storeA(As[cur ^ 1]);
        __syncthreads();   // drains A ds_writes (lgkm) + B cp16 (vmcnt), guards reuse
    }

    if (z == 2) {
#pragma unroll
        for (int mt = 0; mt < 4; mt++)
#pragma unroll
            for (int nt = 0; nt < 4; nt++) {
                int m = m0 + wm + mt * 16 + quad * 4;   // s-dim base (4 consecutive)
                int n = n0 + wn + nt * 16 + l15;        // d-dim
                bf16x4 o4;
#pragma unroll
                for (int r = 0; r < 4; r++) o4[r] = (bf16_t)acc[mt][nt][r];
                size_t vrow = (size_t)((m >> 11) * 16 + (n >> 6)) * 64 + (n & 63);
                int ml = m & 2047;
                int mp = (ml & ~31) | (((ml >> 2) & 3) << 3) | (((ml >> 4) & 1) << 2);
                *reinterpret_cast<bf16x4*>(&Vt[vrow * S_ + mp]) = o4;
            }
    } else {
        bf16_t* Co = (z == 0) ? Qp : Kp;
#pragma unroll
        for (int mt = 0; mt < 4; mt++)
#pragma unroll
            for (int nt = 0; nt < 4; nt++)
#pragma unroll
                for (int r = 0; r < 4; r++) {
                    int m = m0 + wm + mt * 16 + quad * 4 + r;
                    int n = n0 + wn + nt * 16 + l15;
                    Co[(size_t)m * 1024 + n] = (bf16_t)(acc[mt][nt][r] * scale);
                }
    }
}

// ---------------- output GEMM: out[8192 x 1024] f32 = Ao * Wo^T ----------------
__global__ __launch_bounds__(256) void gemm_out(const bf16_t* __restrict__ A,
                                                const bf16_t* __restrict__ Bt,
                                                float* __restrict__ C) {
    __shared__ bf16_t As[2][128 * 32];
    __shared__ bf16_t Bs[2][128 * 32];
    const int K = 1024;
    int tid  = threadIdx.x;
    int lane = tid & 63;
    int w    = tid >> 6;
    int l15  = lane & 15, quad = lane >> 4;

    int bid = blockIdx.x;
    int xcd = bid & 7, idx = bid >> 3;
    int m0 = (xcd * 8 + (idx & 7)) * 128;   // 8 m-blocks per XCD
    int n0 = (idx >> 3) * 128;
    int wm = (w >> 1) * 64, wn = (w & 1) * 64;

    const bf16_t* Ag = A  + (size_t)(m0 + (tid >> 2)) * K + (tid & 3) * 8;
    const bf16_t* Bg = Bt + (size_t)(n0 + (tid >> 2)) * K + (tid & 3) * 8;

    f32x4 acc[4][4] = {};

    async_cp16(Ag,                  &As[0][tid * 8]);
    async_cp16(Ag + (size_t)64 * K, &As[0][tid * 8 + 2048]);
    async_cp16(Bg,                  &Bs[0][tid * 8]);
    async_cp16(Bg + (size_t)64 * K, &Bs[0][tid * 8 + 2048]);
    __syncthreads();

    for (int k0 = 0; k0 < K; k0 += 32) {
        int cur = (k0 >> 5) & 1;
        if (k0 + 32 < K) {
            int nxt = cur ^ 1;
            async_cp16(Ag + k0 + 32,                  &As[nxt][tid * 8]);
            async_cp16(Ag + k0 + 32 + (size_t)64 * K, &As[nxt][tid * 8 + 2048]);
            async_cp16(Bg + k0 + 32,                  &Bs[nxt][tid * 8]);
            async_cp16(Bg + k0 + 32 + (size_t)64 * K, &Bs[nxt][tid * 8 + 2048]);
        }
        bf16x8 af[4], bfr[4];
#pragma unroll
        for (int t = 0; t < 4; t++) {
            af[t]  = *reinterpret_cast<const bf16x8*>(&As[cur][(wm + t * 16 + l15) * 32 + quad * 8]);
            bfr[t] = *reinterpret_cast<const bf16x8*>(&Bs[cur][(wn + t * 16 + l15) * 32 + quad * 8]);
        }
#pragma unroll
        for (int mt = 0; mt < 4; mt++)
#pragma unroll
            for (int nt = 0; nt < 4; nt++)
                acc[mt][nt] = __builtin_amdgcn_mfma_f32_16x16x32_bf16(af[mt], bfr[nt], acc[mt][nt], 0, 0, 0);
        __syncthreads();
    }

#pragma unroll
    for (int mt = 0; mt < 4; mt++)
#pragma unroll
        for (int nt = 0; nt < 4; nt++)
#pragma unroll
            for (int r = 0; r < 4; r++) {
                int m = m0 + wm + mt * 16 + quad * 4 + r;
                int n = n0 + wn + nt * 16 + l15;
                C[(size_t)m * 1024 + n] = acc[mt][nt][r];
            }
}

// ---------------- fused masked attention ----------------
// QBLK=64 (4 waves x 16 q-rows), 2048 WGs, LPT batch order + head clustering.
// K/V double-buffered via swizzled-source global_load_lds (16B-slot XOR row&7,
// applied on the GLOBAL source address and on every LDS read).
// V^T arrives pre-permuted into A-frag k-order (see qkv_gemm z=2), so PV
// fragments are single contiguous b128 reads -- no b64 pairs, no repacking.
__global__ __launch_bounds__(256) void attn_fused(const bf16_t* __restrict__ Qp,
                                                  const bf16_t* __restrict__ Kp,
                                                  const bf16_t* __restrict__ Vt,
                                                  const int* __restrict__ vlen_p,
                                                  bf16_t* __restrict__ Out) {
    __shared__ bf16_t smem[4][64 * 64];   // [0]=K0 (+epilogue T), [1]=V0, [2]=K1 (+Q prologue), [3]=V1

    int tid  = threadIdx.x;
    int lane = tid & 63, w = tid >> 6;
    int l15  = lane & 15, quad = lane >> 4;

    // ---- LPT + XCD-clustered tile decode ----
    int nk[4], ord[4] = {0, 1, 2, 3};
#pragma unroll
    for (int i = 0; i < 4; i++) nk[i] = (vlen_p[i] + 63) >> 6;
#pragma unroll
    for (int i = 0; i < 3; i++)
#pragma unroll
        for (int j = 0; j < 3 - i; j++)
            if (nk[ord[j + 1]] > nk[ord[j]]) { int t = ord[j]; ord[j] = ord[j + 1]; ord[j + 1] = t; }

    int bid  = blockIdx.x;
    int b    = ord[bid >> 9];              // heaviest batch first in dispatch order
    int t    = bid & 511;
    int h    = (t & 7) * 2 + ((t >> 3) & 1);  // 2 heads per XCD slot -> K/V L2 locality
    int qblk = t >> 4;                        // 0..31
    int vlen = vlen_p[b];
    int nkb  = (vlen + 63) >> 6;

    const bf16_t* Qg = Qp + (size_t)(b * S_ + qblk * 64) * D_ + h * 64;
    const bf16_t* Kg = Kp + (size_t)b * S_ * D_ + h * 64;
    const bf16_t* Vg = Vt + (size_t)(b * 16 + h) * 64 * S_;

    // per-lane staging addresses (incremental; XOR source swizzle baked in)
    int r0 = tid >> 3, s0 = tid & 7;
    int sx = (s0 ^ (r0 & 7)) * 8;            // (r0+32)&7 == r0&7
    const bf16_t* kS0 = Kg + (size_t)r0 * D_ + sx;
    const bf16_t* kS1 = kS0 + (size_t)32 * D_;
    const bf16_t* vS0 = Vg + (size_t)r0 * S_ + sx;
    const bf16_t* vS1 = vS0 + (size_t)32 * S_;

    // prologue: Q -> smem[2], K0 -> smem[0], V0 -> smem[1]
    {
        const bf16_t* qS0 = Qg + (size_t)r0 * D_ + sx;
        async_cp16(qS0,                   smem[2] + tid * 8);
        async_cp16(qS0 + (size_t)32 * D_, smem[2] + tid * 8 + 2048);
        async_cp16(kS0, smem[0] + tid * 8);
        async_cp16(kS1, smem[0] + tid * 8 + 2048);
        async_cp16(vS0, smem[1] + tid * 8);
        async_cp16(vS1, smem[1] + tid * 8 + 2048);
    }
    __syncthreads();

    bf16x8 qf[2];
    {
        int row = w * 16 + l15, x = row & 7;
#pragma unroll
        for (int kk = 0; kk < 2; kk++)
            qf[kk] = *reinterpret_cast<const bf16x8*>(&smem[2][row * 64 + ((kk * 4 + quad) ^ x) * 8]);
    }
    __syncthreads();   // all waves done with Q before kb=0 prefetch overwrites smem[2]

    f32x4 o[4] = {};
    float l_st = 0.f;

    for (int kb = 0; kb < nkb; kb++) {
        int cur = kb & 1;
        if (kb + 1 < nkb) {
            int nxt = cur ^ 1;
            kS0 += (size_t)64 * D_; kS1 += (size_t)64 * D_;
            vS0 += 64;              vS1 += 64;
            async_cp16(kS0, smem[nxt * 2]     + tid * 8);
            async_cp16(kS1, smem[nxt * 2]     + tid * 8 + 2048);
            async_cp16(vS0, smem[nxt * 2 + 1] + tid * 8);
            async_cp16(vS1, smem[nxt * 2 + 1] + tid * 8 + 2048);
        }
        const bf16_t* Kc = smem[cur * 2];
        const bf16_t* Vc = smem[cur * 2 + 1];

        // St = K Q^T  (rows = k, cols = this wave's 16 q)
        f32x4 sc[4] = {};
#pragma unroll
        for (int nt = 0; nt < 4; nt++) {
            int row = nt * 16 + l15, x = row & 7;
#pragma unroll
            for (int kk = 0; kk < 2; kk++) {
                bf16x8 kf = *reinterpret_cast<const bf16x8*>(&Kc[row * 64 + ((kk * 4 + quad) ^ x) * 8]);
                sc[nt] = __builtin_amdgcn_mfma_f32_16x16x32_bf16(kf, qf[kk], sc[nt], 0, 0, 0);
            }
        }

        // max-free softmax: p = exp2(st), scale baked into Q projection
        bool partial = (vlen & 63) && (kb == nkb - 1);
        bf16x8 pf[2];
        float lacc = 0.f;
        if (!partial) {
#pragma unroll
            for (int nt = 0; nt < 4; nt++)
#pragma unroll
                for (int r = 0; r < 4; r++) {
                    float p = __builtin_exp2f(sc[nt][r]);
                    lacc += p;
                    pf[nt >> 1][(nt & 1) * 4 + r] = (bf16_t)p;
                }
        } else {
#pragma unroll
            for (int nt = 0; nt < 4; nt++)
#pragma unroll
                for (int r = 0; r < 4; r++) {
                    float p = __builtin_exp2f(sc[nt][r]);
                    if (kb * 64 + nt * 16 + quad * 4 + r >= vlen) p = 0.f;
                    lacc += p;
                    pf[nt >> 1][(nt & 1) * 4 + r] = (bf16_t)p;
                }
        }
        l_st += lacc;

        // O^T += V^T P^T ; V pre-permuted -> single b128 A-frag per (np,dt)
#pragma unroll
        for (int np = 0; np < 2; np++)
#pragma unroll
            for (int dt = 0; dt < 4; dt++) {
                int row = dt * 16 + l15, x = row & 7;
                bf16x8 vfr = *reinterpret_cast<const bf16x8*>(&Vc[row * 64 + ((np * 4 + quad) ^ x) * 8]);
                o[dt] = __builtin_amdgcn_mfma_f32_16x16x32_bf16(vfr, pf[np], o[dt], 0, 0, 0);
            }

        __syncthreads();  // drains prefetch vmcnt + guards cur-buffer reuse
    }

    float l = l_st;
    l += __shfl_xor(l, 16);
    l += __shfl_xor(l, 32);
    float inv = 1.0f / l;

    // epilogue: O^T -> swizzled T (reuse K0) -> coalesced row-major store
    bf16_t* T = smem[0];
    {
        int row = w * 16 + l15, x = row & 7;
#pragma unroll
        for (int dt = 0; dt < 4; dt++) {
            bf16x4 o4;
#pragma unroll
            for (int r = 0; r < 4; r++) o4[r] = (bf16_t)(o[dt][r] * inv);
            int slot = dt * 2 + (quad >> 1);
            *reinterpret_cast<bf16x4*>(&T[row * 64 + (slot ^ x) * 8 + (quad & 1) * 4]) = o4;
        }
    }
    __syncthreads();
    {
        int row = tid >> 2, ch = tid & 3, x = row & 7;
        size_t obase = (size_t)(b * S_ + qblk * 64 + row) * D_ + h * 64 + ch * 16;
        bf16x8 f0 = *reinterpret_cast<const bf16x8*>(&T[row * 64 + ((ch * 2)     ^ x) * 8]);
        bf16x8 f1 = *reinterpret_cast<const bf16x8*>(&T[row * 64 + ((ch * 2 + 1) ^ x) * 8]);
        *reinterpret_cast<bf16x8*>(&Out[obase])     = f0;
        *reinterpret_cast<bf16x8*>(&Out[obase + 8]) = f1;
    }
}

extern "C" void kernel_launch(void* const* d_in, const int* in_sizes, int n_in,
                              void* d_out, int out_size, void* d_ws, size_t ws_size,
                              hipStream_t stream) {
    const float* q  = (const float*)d_in[0];
    const float* k  = (const float*)d_in[1];
    const float* v  = (const float*)d_in[2];
    const int*   vl = (const int*)d_in[3];
    const float* Wq = (const float*)d_in[4];
    const float* Wk = (const float*)d_in[5];
    const float* Wv = (const float*)d_in[6];
    const float* Wo = (const float*)d_in[7];
    float* out = (float*)d_out;

    bf16_t* ws = (bf16_t*)d_ws;
    const size_t SD = (size_t)8192 * 1024;
    const size_t WW = (size_t)1024 * 1024;
    bf16_t* tmpB = ws + SD;        // attn output
    bf16_t* Qp   = ws + 2 * SD;
    bf16_t* Kp   = ws + 3 * SD;
    bf16_t* Vt   = ws + 4 * SD;    // per-head V^T, s pre-permuted to A-frag order
    bf16_t* Wqb  = ws + 5 * SD;
    bf16_t* Wkb  = Wqb + WW;
    bf16_t* Wvb  = Wqb + 2 * WW;
    bf16_t* Wob  = Wqb + 3 * WW;

    const float cs = 0.18033688f;  // (1/8)*log2(e) baked into Q projection
    dim3 blk(256);

    cast4_f32_bf16<<<dim3(1024, 4), blk, 0, stream>>>(Wq, Wk, Wv, Wo, Wqb, Wkb, Wvb, Wob, 262144);
    qkv_gemm<<<dim3(1536), blk, 0, stream>>>(q, k, v, Wqb, Wkb, Wvb, Qp, Kp, Vt, cs);
    attn_fused<<<dim3(2048), blk, 0, stream>>>(Qp, Kp, Vt, vl, tmpB);
    gemm_out<<<dim3(512), blk, 0, stream>>>(tmpB, Wob, out);
}